// Round 6
// baseline (82.671 us; speedup 1.0000x reference)
//
#include <hip/hip_runtime.h>
#include <stdint.h>

// NeRF "mark untrained cells": out[cas][m] = visible(cas, morton_decode(m)) ? density[cas][m] : -1
//
// Math (HW-validated bit-exact, rounds 3-5): c0 = round(w*S0) from LDS table; shared dot
// p = dot(c0,R) as ascending fma chain; cascade c: cam = fmaf(2^c, p, -d) (exact pow2
// scaling commutes with rounding); mask rhs = unfused mul+add; cmp with free |x| modifier.
//
// Round-5 counters: VALUBusy 68%, VGPR 12 -> loop was LDS-issue bound (12 ds_read_b32 vs
// ~39 VALU per cam). This round attacks exactly that ratio:
//  * R + t.R packed into one 48B record -> 3x ds_read_b128 per cam (was 12x b32)
//  * 4 cells/thread (stride-256 in a 1024-cell chunk; coalescing preserved) -> ~156
//    independent VALU ops per cam iter, 4 dependency chains of ILP.
// VALU floor ~34 us; predict 38-43 us.

constexpr int GRIDN  = 128;
constexpr int NCELLS = GRIDN * GRIDN * GRIDN;   // 2097152
constexpr int NCAMS  = 32;
constexpr int CPT    = 4;                        // cells per thread

__device__ __forceinline__ uint32_t compact1by2(uint32_t x) {
    // inverse of reference _part1by2 (valid for 21-bit morton codes)
    x &= 0x09249249u;
    x = (x ^ (x >> 2))  & 0x030c30c3u;
    x = (x ^ (x >> 4))  & 0x0300f00fu;
    x = (x ^ (x >> 8))  & 0x030000ffu;
    x = (x ^ (x >> 16)) & 0x000003ffu;
    return x;
}

__launch_bounds__(256)
__global__ void nerf_mark_kernel(const float* __restrict__ dg,
                                 const float* __restrict__ poses,
                                 const float* __restrict__ intr,
                                 float* __restrict__ out) {
    // one 48B record per camera: R0..R8, dx, dy, dz  (16B aligned -> 3x ds_read_b128)
    __shared__ __align__(16) float sRd[NCAMS * 12];
    __shared__ float sc0[GRIDN];      // c0 table: round((2i/127 - 1) * S0)
    __shared__ float sax[2];          // cx/fx, cy/fy

    constexpr float S0 = 1.0f - 1.0f / 128.0f;                        // 127/128, exact
    constexpr float T0 = 2.0f / 128.0f, T1 = 4.0f / 128.0f, T2 = 8.0f / 128.0f;

    const int tid = threadIdx.x;
    for (int i = tid; i < NCAMS * 12; i += 256) {   // 384 elems > 256 threads: strided!
        int b = i / 12, k = i - b * 12;
        const float* P = poses + b * 16;
        if (k < 9) {
            sRd[i] = P[(k / 3) * 4 + (k % 3)];      // R[j][k']
        } else {
            int kk = k - 9;                          // (t.R)[kk], fma-chain rounding
            sRd[i] = fmaf(P[11], P[8 + kk], fmaf(P[7], P[4 + kk], P[3] * P[kk]));
        }
    }
    if (tid < GRIDN) {
        float w = (2.0f * (float)tid) / 127.0f - 1.0f;   // IEEE ufunc order
        sc0[tid] = __fmul_rn(w, S0);
    }
    if (tid == 0) { sax[0] = intr[2] / intr[0]; sax[1] = intr[3] / intr[1]; }
    __syncthreads();

    const int base = blockIdx.x * (256 * CPT) + tid;     // cells: base + c*256
    float c0x[CPT], c0y[CPT], c0z[CPT];
    #pragma unroll
    for (int c = 0; c < CPT; ++c) {
        const uint32_t um = (uint32_t)(base + c * 256);
        c0x[c] = sc0[compact1by2(um)];
        c0y[c] = sc0[compact1by2(um >> 1)];
        c0z[c] = sc0[compact1by2(um >> 2)];
    }
    const float ax = sax[0], ay = sax[1];

    bool v0[CPT] = {}, v1[CPT] = {}, v2[CPT] = {};

    for (int b = 0; b < NCAMS; ++b) {
        const float4 qa = *reinterpret_cast<const float4*>(&sRd[b * 12]);      // R0..R3
        const float4 qb = *reinterpret_cast<const float4*>(&sRd[b * 12 + 4]);  // R4..R7
        const float4 qc = *reinterpret_cast<const float4*>(&sRd[b * 12 + 8]);  // R8,dx,dy,dz

        #pragma unroll
        for (int c = 0; c < CPT; ++c) {
            // shared dot p = dot(c0, R[:,k]), ascending fma chain
            const float px = fmaf(c0z[c], qb.z, fmaf(c0y[c], qa.w, c0x[c] * qa.x));
            const float py = fmaf(c0z[c], qb.w, fmaf(c0y[c], qb.x, c0x[c] * qa.y));
            const float pz = fmaf(c0z[c], qc.x, fmaf(c0y[c], qb.y, c0x[c] * qa.z));

            // cascade 0: cam = p - d
            {
                const float zz = __fsub_rn(pz, qc.w);
                const float xx = __fsub_rn(px, qc.y);
                const float yy = __fsub_rn(py, qc.z);
                v0[c] = v0[c] | ((zz > 0.0f)
                              & (fabsf(xx) < __fadd_rn(__fmul_rn(ax, zz), T0))
                              & (fabsf(yy) < __fadd_rn(__fmul_rn(ay, zz), T0)));
            }
            // cascade 1: cam = 2*p - d (exact pow2 scaling, bit-identical)
            {
                const float zz = fmaf(2.0f, pz, -qc.w);
                const float xx = fmaf(2.0f, px, -qc.y);
                const float yy = fmaf(2.0f, py, -qc.z);
                v1[c] = v1[c] | ((zz > 0.0f)
                              & (fabsf(xx) < __fadd_rn(__fmul_rn(ax, zz), T1))
                              & (fabsf(yy) < __fadd_rn(__fmul_rn(ay, zz), T1)));
            }
            // cascade 2: cam = 4*p - d
            {
                const float zz = fmaf(4.0f, pz, -qc.w);
                const float xx = fmaf(4.0f, px, -qc.y);
                const float yy = fmaf(4.0f, py, -qc.z);
                v2[c] = v2[c] | ((zz > 0.0f)
                              & (fabsf(xx) < __fadd_rn(__fmul_rn(ax, zz), T2))
                              & (fabsf(yy) < __fadd_rn(__fmul_rn(ay, zz), T2)));
            }
        }

        bool allv = true;
        #pragma unroll
        for (int c = 0; c < CPT; ++c) allv = allv & v0[c] & v1[c] & v2[c];
        if (__all(allv)) break;                      // single wave-uniform early exit
    }

    #pragma unroll
    for (int c = 0; c < CPT; ++c) {
        const int m = base + c * 256;
        out[m]              = v0[c] ? dg[m]              : -1.0f;
        out[NCELLS + m]     = v1[c] ? dg[NCELLS + m]     : -1.0f;
        out[2 * NCELLS + m] = v2[c] ? dg[2 * NCELLS + m] : -1.0f;
    }
}

extern "C" void kernel_launch(void* const* d_in, const int* in_sizes, int n_in,
                              void* d_out, int out_size, void* d_ws, size_t ws_size,
                              hipStream_t stream) {
    const float* dg    = (const float*)d_in[0];   // (3, 128^3) f32
    const float* poses = (const float*)d_in[1];   // (32, 4, 4) f32
    const float* intr  = (const float*)d_in[2];   // (4,) f32
    float* out = (float*)d_out;                   // (3, 128^3) f32

    nerf_mark_kernel<<<NCELLS / (256 * CPT), 256, 0, stream>>>(dg, poses, intr, out);
}

// Round 7
// 66.712 us; speedup vs baseline: 1.2392x; 1.2392x over previous
//
#include <hip/hip_runtime.h>
#include <stdint.h>

// NeRF "mark untrained cells": out[cas][m] = visible(cas, morton_decode(m)) ? density[cas][m] : -1
//
// Math (HW-validated bit-exact, rounds 3-6): c0 = round(w*S0) from LDS table; shared dot
// p = dot(c0,R) ascending fma chain; cascade c: cam = fmaf(2^c, p, -d) (exact pow2 scaling
// commutes with rounding); mask rhs = unfused mul+add; |x| via free input modifier.
//
// Structure lessons:
//  * round 5 (61.5us, VALUBusy 68%): 1 cell/thread, 8192 blocks, 64-cell break -- GOOD
//    distribution; stall-bound at 12 ds_read_b32 : 39 VALU per cam.
//  * round 6 (82.7us, occ 43%): 4 scattered cells/thread, 2048 blocks -- killed the early
//    exit (needs 1024-cell agreement) AND load balance. REVERTED.
// This round = round-5 structure + (a) 48B packed camera record -> 3x ds_read_b128/cam,
// (b) camera loop unrolled x2 -> ~78 VALU per iter in 2 independent chains vs 6 LDS reads.

constexpr int GRIDN  = 128;
constexpr int NCELLS = GRIDN * GRIDN * GRIDN;   // 2097152
constexpr int NCAMS  = 32;

__device__ __forceinline__ uint32_t compact1by2(uint32_t x) {
    // inverse of reference _part1by2 (valid for 21-bit morton codes)
    x &= 0x09249249u;
    x = (x ^ (x >> 2))  & 0x030c30c3u;
    x = (x ^ (x >> 4))  & 0x0300f00fu;
    x = (x ^ (x >> 8))  & 0x030000ffu;
    x = (x ^ (x >> 16)) & 0x000003ffu;
    return x;
}

struct Vis { bool v0, v1, v2; };

// One camera's full 3-cascade test. Bit-identical fp to validated rounds.
__device__ __forceinline__ Vis cam_test(float c0x, float c0y, float c0z,
                                        float ax, float ay,
                                        float4 qa, float4 qb, float4 qc) {
    constexpr float T0 = 2.0f / 128.0f, T1 = 4.0f / 128.0f, T2 = 8.0f / 128.0f;
    // shared dot p = dot(c0, R[:,k]), ascending fma chain
    const float px = fmaf(c0z, qb.z, fmaf(c0y, qa.w, c0x * qa.x));
    const float py = fmaf(c0z, qb.w, fmaf(c0y, qb.x, c0x * qa.y));
    const float pz = fmaf(c0z, qc.x, fmaf(c0y, qb.y, c0x * qa.z));
    Vis r;
    {   // cascade 0: cam = p - d
        const float zz = __fsub_rn(pz, qc.w);
        const float xx = __fsub_rn(px, qc.y);
        const float yy = __fsub_rn(py, qc.z);
        r.v0 = (zz > 0.0f) & (fabsf(xx) < __fadd_rn(__fmul_rn(ax, zz), T0))
                           & (fabsf(yy) < __fadd_rn(__fmul_rn(ay, zz), T0));
    }
    {   // cascade 1: cam = 2*p - d (exact pow2 scaling)
        const float zz = fmaf(2.0f, pz, -qc.w);
        const float xx = fmaf(2.0f, px, -qc.y);
        const float yy = fmaf(2.0f, py, -qc.z);
        r.v1 = (zz > 0.0f) & (fabsf(xx) < __fadd_rn(__fmul_rn(ax, zz), T1))
                           & (fabsf(yy) < __fadd_rn(__fmul_rn(ay, zz), T1));
    }
    {   // cascade 2: cam = 4*p - d
        const float zz = fmaf(4.0f, pz, -qc.w);
        const float xx = fmaf(4.0f, px, -qc.y);
        const float yy = fmaf(4.0f, py, -qc.z);
        r.v2 = (zz > 0.0f) & (fabsf(xx) < __fadd_rn(__fmul_rn(ax, zz), T2))
                           & (fabsf(yy) < __fadd_rn(__fmul_rn(ay, zz), T2));
    }
    return r;
}

__launch_bounds__(256)
__global__ void nerf_mark_kernel(const float* __restrict__ dg,
                                 const float* __restrict__ poses,
                                 const float* __restrict__ intr,
                                 float* __restrict__ out) {
    // one 48B record per camera: R0..R8, dx, dy, dz  (16B aligned -> 3x ds_read_b128)
    __shared__ __align__(16) float sRd[NCAMS * 12];
    __shared__ float sc0[GRIDN];      // c0 table: round((2i/127 - 1) * S0)
    __shared__ float sax[2];          // cx/fx, cy/fy

    constexpr float S0 = 1.0f - 1.0f / 128.0f;    // 127/128, exact

    const int tid = threadIdx.x;
    for (int i = tid; i < NCAMS * 12; i += 256) {   // 384 elems > 256 threads: strided!
        int b = i / 12, k = i - b * 12;
        const float* P = poses + b * 16;
        if (k < 9) {
            sRd[i] = P[(k / 3) * 4 + (k % 3)];      // R[j][k']
        } else {
            int kk = k - 9;                          // (t.R)[kk], fma-chain rounding
            sRd[i] = fmaf(P[11], P[8 + kk], fmaf(P[7], P[4 + kk], P[3] * P[kk]));
        }
    }
    if (tid < GRIDN) {
        float w = (2.0f * (float)tid) / 127.0f - 1.0f;   // IEEE ufunc order
        sc0[tid] = __fmul_rn(w, S0);
    }
    if (tid == 0) { sax[0] = intr[2] / intr[0]; sax[1] = intr[3] / intr[1]; }
    __syncthreads();

    const int m = blockIdx.x * 256 + tid;
    const uint32_t um = (uint32_t)m;
    const float c0x = sc0[compact1by2(um)];
    const float c0y = sc0[compact1by2(um >> 1)];
    const float c0z = sc0[compact1by2(um >> 2)];
    const float ax = sax[0], ay = sax[1];

    bool v0 = false, v1 = false, v2 = false;

    for (int b = 0; b < NCAMS; b += 2) {
        // camera b and b+1 records: 6x ds_read_b128, two independent VALU chains
        const float4* A = reinterpret_cast<const float4*>(&sRd[b * 12]);
        const float4 qa0 = A[0], qb0 = A[1], qc0 = A[2];
        const float4 qa1 = A[3], qb1 = A[4], qc1 = A[5];

        const Vis r0 = cam_test(c0x, c0y, c0z, ax, ay, qa0, qb0, qc0);
        const Vis r1 = cam_test(c0x, c0y, c0z, ax, ay, qa1, qb1, qc1);

        v0 = v0 | r0.v0 | r1.v0;
        v1 = v1 | r0.v1 | r1.v1;
        v2 = v2 | r0.v2 | r1.v2;

        if (__all(v0 & v1 & v2)) break;   // wave-uniform break, once per cam pair
    }

    out[m]              = v0 ? dg[m]              : -1.0f;
    out[NCELLS + m]     = v1 ? dg[NCELLS + m]     : -1.0f;
    out[2 * NCELLS + m] = v2 ? dg[2 * NCELLS + m] : -1.0f;
}

extern "C" void kernel_launch(void* const* d_in, const int* in_sizes, int n_in,
                              void* d_out, int out_size, void* d_ws, size_t ws_size,
                              hipStream_t stream) {
    const float* dg    = (const float*)d_in[0];   // (3, 128^3) f32
    const float* poses = (const float*)d_in[1];   // (32, 4, 4) f32
    const float* intr  = (const float*)d_in[2];   // (4,) f32
    float* out = (float*)d_out;                   // (3, 128^3) f32

    nerf_mark_kernel<<<NCELLS / 256, 256, 0, stream>>>(dg, poses, intr, out);
}

// Round 8
// 23.981 us; speedup vs baseline: 3.4474x; 2.7819x over previous
//
#include <hip/hip_runtime.h>
#include <stdint.h>

// NeRF "mark untrained cells": out[cas][m] = visible(cas, morton_decode(m)) ? density[cas][m] : -1
//
// Exact per-cell math (HW-validated bit-exact, rounds 3-7): c0 = round(w*S0) table; shared
// dot p = dot(c0,R) ascending fma chain; cascade c: cam = fmaf(2^c, p, -d); mask rhs =
// unfused mul+add; |x| via input modifier.
//
// NEW this round: per-wave camera culling. A wave = one 4x4x4 Morton block. Phase 1: lane
// l classifies camera (l&31) for all 3 cascades with CONSERVATIVE interval arithmetic
// (center/halfwidth of the block in cam space, PAD=1e-3 >> 25x worst-case fp error of the
// exact path, ~1% of min interval radius):
//   certainly-fail  -> camera contributes false to every cell: SKIP exact test
//   certainly-inside-> camera passes for every cell: set v_c wave-wide, no test
//   else "possible" -> exact per-cell test (bit-identical code path)
// __ballot -> wave-uniform masks; fine loop bit-scans only possible cameras (typically 0-4
// of 32). Output bits provably identical; executed VALU work drops ~4-8x.

constexpr int GRIDN  = 128;
constexpr int NCELLS = GRIDN * GRIDN * GRIDN;   // 2097152
constexpr int NCAMS  = 32;

__device__ __forceinline__ uint32_t compact1by2(uint32_t x) {
    // inverse of reference _part1by2 (valid for 21-bit morton codes)
    x &= 0x09249249u;
    x = (x ^ (x >> 2))  & 0x030c30c3u;
    x = (x ^ (x >> 4))  & 0x0300f00fu;
    x = (x ^ (x >> 8))  & 0x030000ffu;
    x = (x ^ (x >> 16)) & 0x000003ffu;
    return x;
}

struct Vis { bool v0, v1, v2; };

// One camera's full 3-cascade EXACT test. Bit-identical fp to validated rounds 5/7.
__device__ __forceinline__ Vis cam_test(float c0x, float c0y, float c0z,
                                        float ax, float ay,
                                        float4 qa, float4 qb, float4 qc) {
    constexpr float T0 = 2.0f / 128.0f, T1 = 4.0f / 128.0f, T2 = 8.0f / 128.0f;
    const float px = fmaf(c0z, qb.z, fmaf(c0y, qa.w, c0x * qa.x));
    const float py = fmaf(c0z, qb.w, fmaf(c0y, qb.x, c0x * qa.y));
    const float pz = fmaf(c0z, qc.x, fmaf(c0y, qb.y, c0x * qa.z));
    Vis r;
    {   const float zz = __fsub_rn(pz, qc.w);
        const float xx = __fsub_rn(px, qc.y);
        const float yy = __fsub_rn(py, qc.z);
        r.v0 = (zz > 0.0f) & (fabsf(xx) < __fadd_rn(__fmul_rn(ax, zz), T0))
                           & (fabsf(yy) < __fadd_rn(__fmul_rn(ay, zz), T0)); }
    {   const float zz = fmaf(2.0f, pz, -qc.w);
        const float xx = fmaf(2.0f, px, -qc.y);
        const float yy = fmaf(2.0f, py, -qc.z);
        r.v1 = (zz > 0.0f) & (fabsf(xx) < __fadd_rn(__fmul_rn(ax, zz), T1))
                           & (fabsf(yy) < __fadd_rn(__fmul_rn(ay, zz), T1)); }
    {   const float zz = fmaf(4.0f, pz, -qc.w);
        const float xx = fmaf(4.0f, px, -qc.y);
        const float yy = fmaf(4.0f, py, -qc.z);
        r.v2 = (zz > 0.0f) & (fabsf(xx) < __fadd_rn(__fmul_rn(ax, zz), T2))
                           & (fabsf(yy) < __fadd_rn(__fmul_rn(ay, zz), T2)); }
    return r;
}

__launch_bounds__(256)
__global__ void nerf_mark_kernel(const float* __restrict__ dg,
                                 const float* __restrict__ poses,
                                 const float* __restrict__ intr,
                                 float* __restrict__ out) {
    // one 48B record per camera: R0..R8, dx, dy, dz  (16B aligned -> 3x ds_read_b128)
    __shared__ __align__(16) float sRd[NCAMS * 12];
    __shared__ float sc0[GRIDN];      // c0 table: round((2i/127 - 1) * S0)
    __shared__ float sax[2];          // cx/fx, cy/fy

    constexpr float S0  = 1.0f - 1.0f / 128.0f;   // 127/128, exact
    constexpr float T0  = 2.0f / 128.0f, T1 = 4.0f / 128.0f, T2 = 8.0f / 128.0f;
    constexpr float PAD = 1e-3f;                  // >> worst-case fp error (~4e-5)

    const int tid = threadIdx.x;
    for (int i = tid; i < NCAMS * 12; i += 256) {   // 384 elems > 256 threads: strided!
        int b = i / 12, k = i - b * 12;
        const float* P = poses + b * 16;
        if (k < 9) {
            sRd[i] = P[(k / 3) * 4 + (k % 3)];      // R[j][k']
        } else {
            int kk = k - 9;                          // (t.R)[kk], fma-chain rounding
            sRd[i] = fmaf(P[11], P[8 + kk], fmaf(P[7], P[4 + kk], P[3] * P[kk]));
        }
    }
    if (tid < GRIDN) {
        float w = (2.0f * (float)tid) / 127.0f - 1.0f;   // IEEE ufunc order
        sc0[tid] = __fmul_rn(w, S0);
    }
    if (tid == 0) { sax[0] = intr[2] / intr[0]; sax[1] = intr[3] / intr[1]; }
    __syncthreads();

    const int m = blockIdx.x * 256 + tid;
    const uint32_t um = (uint32_t)m;
    const float c0x = sc0[compact1by2(um)];
    const float c0y = sc0[compact1by2(um >> 1)];
    const float c0z = sc0[compact1by2(um >> 2)];
    const float ax = sax[0], ay = sax[1];

    // ---- phase 1: wave's 4x4x4 block geometry (wave-uniform) ----
    const uint32_t uwb = um & ~63u;              // first cell of this wave's block
    const int X0 = compact1by2(uwb);             // low 2 bits are 0; block = X0..X0+3
    const int Y0 = compact1by2(uwb >> 1);
    const int Z0 = compact1by2(uwb >> 2);
    const float gxl = sc0[X0], gxh = sc0[X0 + 3];   // sc0 is monotonic
    const float gyl = sc0[Y0], gyh = sc0[Y0 + 3];
    const float gzl = sc0[Z0], gzh = sc0[Z0 + 3];
    const float gcx = 0.5f * (gxl + gxh), ghx = 0.5f * (gxh - gxl);
    const float gcy = 0.5f * (gyl + gyh), ghy = 0.5f * (gyh - gyl);
    const float gcz = 0.5f * (gzl + gzh), ghz = 0.5f * (gzh - gzl);

    // lane l classifies camera (l & 31); lanes 32..63 duplicate (ballot low 32 bits used)
    const int cb = tid & 31;
    bool po0, in0, po1, in1, po2, in2;
    {
        const float4* A = reinterpret_cast<const float4*>(&sRd[cb * 12]);
        const float4 qa = A[0], qb = A[1], qc = A[2];
        const float pcx = fmaf(gcz, qb.z, fmaf(gcy, qa.w, gcx * qa.x));
        const float pcy = fmaf(gcz, qb.w, fmaf(gcy, qb.x, gcx * qa.y));
        const float pcz = fmaf(gcz, qc.x, fmaf(gcy, qb.y, gcx * qa.z));
        const float rdx = fmaf(ghz, fabsf(qb.z), fmaf(ghy, fabsf(qa.w), ghx * fabsf(qa.x)));
        const float rdy = fmaf(ghz, fabsf(qb.w), fmaf(ghy, fabsf(qb.x), ghx * fabsf(qa.y)));
        const float rdz = fmaf(ghz, fabsf(qc.x), fmaf(ghy, fabsf(qb.y), ghx * fabsf(qa.z)));
        const float ddx = qc.y, ddy = qc.z, ddz = qc.w;

        auto classify = [&](float s, float T, bool& poss, bool& allin) {
            const float zc = fmaf(s, pcz, -ddz), zr = s * rdz;
            const float zmax = zc + zr, zmin = zc - zr;
            const float xc = fmaf(s, pcx, -ddx), xr = s * rdx, axc = fabsf(xc);
            const float yc = fmaf(s, pcy, -ddy), yr = s * rdy, ayc = fabsf(yc);
            const float rxmax = fmaf(ax, zmax, T), rxmin = fmaf(ax, zmin, T);
            const float rymax = fmaf(ay, zmax, T), rymin = fmaf(ay, zmin, T);
            const bool failz = (zmax <= -PAD);                 // all cells: zz <= 0
            const bool failx = (axc - xr >= rxmax + PAD);      // all cells: |xx| >= rhs
            const bool faily = (ayc - yr >= rymax + PAD);
            poss  = !(failz | failx | faily);
            allin = (zmin >= PAD) & (axc + xr <= rxmin - PAD)
                                  & (ayc + yr <= rymin - PAD); // all cells pass
        };
        classify(1.0f, T0, po0, in0);
        classify(2.0f, T1, po1, in1);
        classify(4.0f, T2, po2, in2);
    }

    const uint32_t allin0 = (uint32_t)__ballot(in0);
    const uint32_t allin1 = (uint32_t)__ballot(in1);
    const uint32_t allin2 = (uint32_t)__ballot(in2);
    const uint32_t poss0  = (uint32_t)__ballot(po0);
    const uint32_t poss1  = (uint32_t)__ballot(po1);
    const uint32_t poss2  = (uint32_t)__ballot(po2);

    bool v0 = (allin0 != 0u), v1 = (allin1 != 0u), v2 = (allin2 != 0u);

    // ---- phase 2: exact per-cell tests, only for silhouette cameras ----
    uint32_t u = (v0 ? 0u : poss0) | (v1 ? 0u : poss1) | (v2 ? 0u : poss2);
    while (u) {
        const int b = __ffs(u) - 1;
        u &= u - 1;
        const float4* B = reinterpret_cast<const float4*>(&sRd[b * 12]);
        const Vis r = cam_test(c0x, c0y, c0z, ax, ay, B[0], B[1], B[2]);
        v0 |= r.v0; v1 |= r.v1; v2 |= r.v2;
        if (__all(v0 & v1 & v2)) break;
    }

    out[m]              = v0 ? dg[m]              : -1.0f;
    out[NCELLS + m]     = v1 ? dg[NCELLS + m]     : -1.0f;
    out[2 * NCELLS + m] = v2 ? dg[2 * NCELLS + m] : -1.0f;
}

extern "C" void kernel_launch(void* const* d_in, const int* in_sizes, int n_in,
                              void* d_out, int out_size, void* d_ws, size_t ws_size,
                              hipStream_t stream) {
    const float* dg    = (const float*)d_in[0];   // (3, 128^3) f32
    const float* poses = (const float*)d_in[1];   // (32, 4, 4) f32
    const float* intr  = (const float*)d_in[2];   // (4,) f32
    float* out = (float*)d_out;                   // (3, 128^3) f32

    nerf_mark_kernel<<<NCELLS / 256, 256, 0, stream>>>(dg, poses, intr, out);
}

// Round 9
// 23.780 us; speedup vs baseline: 3.4766x; 1.0085x over previous
//
#include <hip/hip_runtime.h>
#include <stdint.h>

// NeRF "mark untrained cells": out[cas][m] = visible(cas, morton_decode(m)) ? density[cas][m] : -1
//
// Exact per-cell math (HW-validated bit-exact, rounds 3-8) + conservative per-wave camera
// culling (round 8, validated: 24.0us, absmax 0.0). This round:
//  * BLOCK 256 -> 1024: prologue (staging + sc0 table + barriers) amortized over 16 waves
//    instead of 4. Early exit is per-wave (64-cell block) -- granularity unchanged.
//  * phase 2 skips cascades per camera via WAVE-UNIFORM scalar branches on the ballot
//    masks (s_cbranch, no divergence): a silhouette cam usually grazes only 1 cascade.

constexpr int GRIDN  = 128;
constexpr int NCELLS = GRIDN * GRIDN * GRIDN;   // 2097152
constexpr int NCAMS  = 32;
constexpr int BLOCK  = 1024;

__device__ __forceinline__ uint32_t compact1by2(uint32_t x) {
    // inverse of reference _part1by2 (valid for 21-bit morton codes)
    x &= 0x09249249u;
    x = (x ^ (x >> 2))  & 0x030c30c3u;
    x = (x ^ (x >> 4))  & 0x0300f00fu;
    x = (x ^ (x >> 8))  & 0x030000ffu;
    x = (x ^ (x >> 16)) & 0x000003ffu;
    return x;
}

__launch_bounds__(BLOCK)
__global__ void nerf_mark_kernel(const float* __restrict__ dg,
                                 const float* __restrict__ poses,
                                 const float* __restrict__ intr,
                                 float* __restrict__ out) {
    // one 48B record per camera: R0..R8, dx, dy, dz  (16B aligned -> 3x ds_read_b128)
    __shared__ __align__(16) float sRd[NCAMS * 12];
    __shared__ float sc0[GRIDN];      // c0 table: round((2i/127 - 1) * S0)
    __shared__ float sax[2];          // cx/fx, cy/fy

    constexpr float S0  = 1.0f - 1.0f / 128.0f;   // 127/128, exact
    constexpr float T0  = 2.0f / 128.0f, T1 = 4.0f / 128.0f, T2 = 8.0f / 128.0f;
    constexpr float PAD = 1e-3f;                  // >> worst-case fp error (~4e-5)

    const int tid = threadIdx.x;
    if (tid < NCAMS * 12) {                        // 384 < 1024: single pass
        int b = tid / 12, k = tid - b * 12;
        const float* P = poses + b * 16;
        if (k < 9) {
            sRd[tid] = P[(k / 3) * 4 + (k % 3)];   // R[j][k']
        } else {
            int kk = k - 9;                         // (t.R)[kk], fma-chain rounding
            sRd[tid] = fmaf(P[11], P[8 + kk], fmaf(P[7], P[4 + kk], P[3] * P[kk]));
        }
    }
    if (tid < GRIDN) {
        float w = (2.0f * (float)tid) / 127.0f - 1.0f;   // IEEE ufunc order
        sc0[tid] = __fmul_rn(w, S0);
    }
    if (tid == 0) { sax[0] = intr[2] / intr[0]; sax[1] = intr[3] / intr[1]; }
    __syncthreads();

    const int m = blockIdx.x * BLOCK + tid;
    const uint32_t um = (uint32_t)m;
    const float c0x = sc0[compact1by2(um)];
    const float c0y = sc0[compact1by2(um >> 1)];
    const float c0z = sc0[compact1by2(um >> 2)];
    const float ax = sax[0], ay = sax[1];

    // ---- phase 1: this wave's 4x4x4 block geometry (wave-uniform) ----
    const uint32_t uwb = um & ~63u;              // first cell of this wave's block
    const int X0 = compact1by2(uwb);             // block spans X0..X0+3 etc.
    const int Y0 = compact1by2(uwb >> 1);
    const int Z0 = compact1by2(uwb >> 2);
    const float gxl = sc0[X0], gxh = sc0[X0 + 3];   // sc0 monotonic
    const float gyl = sc0[Y0], gyh = sc0[Y0 + 3];
    const float gzl = sc0[Z0], gzh = sc0[Z0 + 3];
    const float gcx = 0.5f * (gxl + gxh), ghx = 0.5f * (gxh - gxl);
    const float gcy = 0.5f * (gyl + gyh), ghy = 0.5f * (gyh - gyl);
    const float gcz = 0.5f * (gzl + gzh), ghz = 0.5f * (gzh - gzl);

    // lane l classifies camera (l & 31); lanes 32..63 duplicate (low 32 ballot bits used)
    const int cb = tid & 31;
    bool po0, in0, po1, in1, po2, in2;
    {
        const float4* A = reinterpret_cast<const float4*>(&sRd[cb * 12]);
        const float4 qa = A[0], qb = A[1], qc = A[2];
        const float pcx = fmaf(gcz, qb.z, fmaf(gcy, qa.w, gcx * qa.x));
        const float pcy = fmaf(gcz, qb.w, fmaf(gcy, qb.x, gcx * qa.y));
        const float pcz = fmaf(gcz, qc.x, fmaf(gcy, qb.y, gcx * qa.z));
        const float rdx = fmaf(ghz, fabsf(qb.z), fmaf(ghy, fabsf(qa.w), ghx * fabsf(qa.x)));
        const float rdy = fmaf(ghz, fabsf(qb.w), fmaf(ghy, fabsf(qb.x), ghx * fabsf(qa.y)));
        const float rdz = fmaf(ghz, fabsf(qc.x), fmaf(ghy, fabsf(qb.y), ghx * fabsf(qa.z)));
        const float ddx = qc.y, ddy = qc.z, ddz = qc.w;

        auto classify = [&](float s, float T, bool& poss, bool& allin) {
            const float zc = fmaf(s, pcz, -ddz), zr = s * rdz;
            const float zmax = zc + zr, zmin = zc - zr;
            const float xc = fmaf(s, pcx, -ddx), xr = s * rdx, axc = fabsf(xc);
            const float yc = fmaf(s, pcy, -ddy), yr = s * rdy, ayc = fabsf(yc);
            const float rxmax = fmaf(ax, zmax, T), rxmin = fmaf(ax, zmin, T);
            const float rymax = fmaf(ay, zmax, T), rymin = fmaf(ay, zmin, T);
            const bool failz = (zmax <= -PAD);                 // all cells: zz <= 0
            const bool failx = (axc - xr >= rxmax + PAD);      // all cells: |xx| >= rhs
            const bool faily = (ayc - yr >= rymax + PAD);
            poss  = !(failz | failx | faily);
            allin = (zmin >= PAD) & (axc + xr <= rxmin - PAD)
                                  & (ayc + yr <= rymin - PAD); // all cells pass
        };
        classify(1.0f, T0, po0, in0);
        classify(2.0f, T1, po1, in1);
        classify(4.0f, T2, po2, in2);
    }

    const uint32_t allin0 = (uint32_t)__ballot(in0);
    const uint32_t allin1 = (uint32_t)__ballot(in1);
    const uint32_t allin2 = (uint32_t)__ballot(in2);
    const uint32_t poss0  = (uint32_t)__ballot(po0);
    const uint32_t poss1  = (uint32_t)__ballot(po1);
    const uint32_t poss2  = (uint32_t)__ballot(po2);

    bool v0 = (allin0 != 0u), v1 = (allin1 != 0u), v2 = (allin2 != 0u);

    // ---- phase 2: exact per-cell tests for silhouette cameras only ----
    // uniform masks: skip cascades already satisfied wave-wide, and per-camera skip
    // cascades the camera provably can't affect (scalar branches, no divergence).
    const uint32_t u0 = v0 ? 0u : poss0;
    const uint32_t u1 = v1 ? 0u : poss1;
    const uint32_t u2 = v2 ? 0u : poss2;
    uint32_t u = u0 | u1 | u2;
    while (u) {
        const int b = __ffs(u) - 1;
        const uint32_t bit = 1u << b;
        u &= u - 1;
        const float4* B = reinterpret_cast<const float4*>(&sRd[b * 12]);
        const float4 qa = B[0], qb = B[1], qc = B[2];
        // shared dot p = dot(c0, R[:,k]), ascending fma chain (bit-exact path)
        const float px = fmaf(c0z, qb.z, fmaf(c0y, qa.w, c0x * qa.x));
        const float py = fmaf(c0z, qb.w, fmaf(c0y, qb.x, c0x * qa.y));
        const float pz = fmaf(c0z, qc.x, fmaf(c0y, qb.y, c0x * qa.z));
        if (u0 & bit) {   // cascade 0: cam = p - d
            const float zz = __fsub_rn(pz, qc.w);
            const float xx = __fsub_rn(px, qc.y);
            const float yy = __fsub_rn(py, qc.z);
            v0 = v0 | ((zz > 0.0f) & (fabsf(xx) < __fadd_rn(__fmul_rn(ax, zz), T0))
                                   & (fabsf(yy) < __fadd_rn(__fmul_rn(ay, zz), T0)));
        }
        if (u1 & bit) {   // cascade 1: cam = 2*p - d (exact pow2 scaling)
            const float zz = fmaf(2.0f, pz, -qc.w);
            const float xx = fmaf(2.0f, px, -qc.y);
            const float yy = fmaf(2.0f, py, -qc.z);
            v1 = v1 | ((zz > 0.0f) & (fabsf(xx) < __fadd_rn(__fmul_rn(ax, zz), T1))
                                   & (fabsf(yy) < __fadd_rn(__fmul_rn(ay, zz), T1)));
        }
        if (u2 & bit) {   // cascade 2: cam = 4*p - d
            const float zz = fmaf(4.0f, pz, -qc.w);
            const float xx = fmaf(4.0f, px, -qc.y);
            const float yy = fmaf(4.0f, py, -qc.z);
            v2 = v2 | ((zz > 0.0f) & (fabsf(xx) < __fadd_rn(__fmul_rn(ax, zz), T2))
                                   & (fabsf(yy) < __fadd_rn(__fmul_rn(ay, zz), T2)));
        }
        if (__all(v0 & v1 & v2)) break;
    }

    out[m]              = v0 ? dg[m]              : -1.0f;
    out[NCELLS + m]     = v1 ? dg[NCELLS + m]     : -1.0f;
    out[2 * NCELLS + m] = v2 ? dg[2 * NCELLS + m] : -1.0f;
}

extern "C" void kernel_launch(void* const* d_in, const int* in_sizes, int n_in,
                              void* d_out, int out_size, void* d_ws, size_t ws_size,
                              hipStream_t stream) {
    const float* dg    = (const float*)d_in[0];   // (3, 128^3) f32
    const float* poses = (const float*)d_in[1];   // (32, 4, 4) f32
    const float* intr  = (const float*)d_in[2];   // (4,) f32
    float* out = (float*)d_out;                   // (3, 128^3) f32

    nerf_mark_kernel<<<NCELLS / BLOCK, BLOCK, 0, stream>>>(dg, poses, intr, out);
}

// Round 10
// 20.753 us; speedup vs baseline: 3.9836x; 1.1459x over previous
//
#include <hip/hip_runtime.h>
#include <stdint.h>

// NeRF "mark untrained cells": out[cas][m] = visible(cas, morton_decode(m)) ? density[cas][m] : -1
//
// Exact per-cell math (HW-validated bit-exact, rounds 3-9) + conservative per-wave camera
// culling (rounds 8/9, validated 24us / absmax 0.0). This round attacks per-wave FIXED
// cost (the only unvaried term after two neutral rounds):
//  * 2 cells/thread: wave = 128 contiguous Morton cells (8x4x4 box); lane l owns wb+l and
//    wb+64+l (x differs by +4 -> same bit-exact fma chain, different sc0 entry).
//    Waves 32768 -> 16384; decode/classify/ballot/epilogue cost per cell halves.
//  * 5-plane SAT classifier (z, ax*z+-x, ay*z+-y as linear forms; center dot + abs-coef
//    dot) -- couples x<->z, strictly tighter than the old decoupled interval test;
//    offsets the 2x bigger box.
//  * in-block Morton decode from lane bits (~12 ops vs 3x compact1by2).

constexpr int GRIDN  = 128;
constexpr int NCELLS = GRIDN * GRIDN * GRIDN;   // 2097152
constexpr int NCAMS  = 32;
constexpr int BLOCK  = 1024;
constexpr int CPB    = 2 * BLOCK;               // cells per block

__device__ __forceinline__ uint32_t compact1by2(uint32_t x) {
    // inverse of reference _part1by2 (valid for 21-bit morton codes)
    x &= 0x09249249u;
    x = (x ^ (x >> 2))  & 0x030c30c3u;
    x = (x ^ (x >> 4))  & 0x0300f00fu;
    x = (x ^ (x >> 8))  & 0x030000ffu;
    x = (x ^ (x >> 16)) & 0x000003ffu;
    return x;
}

__launch_bounds__(BLOCK)
__global__ void nerf_mark_kernel(const float* __restrict__ dg,
                                 const float* __restrict__ poses,
                                 const float* __restrict__ intr,
                                 float* __restrict__ out) {
    // one 48B record per camera: R0..R8, dx, dy, dz  (16B aligned -> 3x ds_read_b128)
    __shared__ __align__(16) float sRd[NCAMS * 12];
    __shared__ float sc0[GRIDN];      // c0 table: round((2i/127 - 1) * S0)
    __shared__ float sax[2];          // cx/fx, cy/fy

    constexpr float S0  = 1.0f - 1.0f / 128.0f;   // 127/128, exact
    constexpr float T0  = 2.0f / 128.0f, T1 = 4.0f / 128.0f, T2 = 8.0f / 128.0f;
    constexpr float PAD = 1e-3f;                  // >> worst-case fp error (~4e-5)

    const int tid = threadIdx.x;
    if (tid < NCAMS * 12) {                        // 384 < 1024: single pass
        int b = tid / 12, k = tid - b * 12;
        const float* P = poses + b * 16;
        if (k < 9) {
            sRd[tid] = P[(k / 3) * 4 + (k % 3)];   // R[j][k']
        } else {
            int kk = k - 9;                         // (t.R)[kk], fma-chain rounding
            sRd[tid] = fmaf(P[11], P[8 + kk], fmaf(P[7], P[4 + kk], P[3] * P[kk]));
        }
    }
    if (tid < GRIDN) {
        float w = (2.0f * (float)tid) / 127.0f - 1.0f;   // IEEE ufunc order
        sc0[tid] = __fmul_rn(w, S0);
    }
    if (tid == 0) { sax[0] = intr[2] / intr[0]; sax[1] = intr[3] / intr[1]; }
    __syncthreads();

    const int lane = tid & 63;
    const uint32_t wbase = (uint32_t)blockIdx.x * CPB + ((uint32_t)(tid >> 6)) * 128u;

    // in-block morton decode from lane bits (cells wbase+lane and wbase+64+lane)
    const int xl = (lane & 1) | ((lane >> 2) & 2);        // bits b0,b3
    const int yl = ((lane >> 1) & 1) | ((lane >> 3) & 2); // bits b1,b4
    const int zl = ((lane >> 2) & 1) | ((lane >> 4) & 2); // bits b2,b5
    const int X0 = compact1by2(wbase);            // multiple of 8; block x: X0..X0+7
    const int Y0 = compact1by2(wbase >> 1);       // multiple of 4
    const int Z0 = compact1by2(wbase >> 2);       // multiple of 4
    const float cAx = sc0[X0 + xl];               // cell A x-coord (exact table value)
    const float cBx = sc0[X0 + xl + 4];           // cell B: +64 morton = x+4
    const float c0y = sc0[Y0 + yl];
    const float c0z = sc0[Z0 + zl];
    const float ax = sax[0], ay = sax[1];

    // ---- phase 1: wave box (8x4x4 cells) center/halfwidth; sc0 monotonic ----
    const float gxl = sc0[X0], gxh = sc0[X0 + 7];
    const float gyl = sc0[Y0], gyh = sc0[Y0 + 3];
    const float gzl = sc0[Z0], gzh = sc0[Z0 + 3];
    const float gcx = 0.5f * (gxl + gxh), ghx = 0.5f * (gxh - gxl);
    const float gcy = 0.5f * (gyl + gyh), ghy = 0.5f * (gyh - gyl);
    const float gcz = 0.5f * (gzl + gzh), ghz = 0.5f * (gzh - gzl);

    // lane l classifies camera (l & 31); lanes 32..63 duplicate (low 32 ballot bits used)
    const int cb = lane & 31;
    bool po0, in0, po1, in1, po2, in2;
    {
        const float4* A = reinterpret_cast<const float4*>(&sRd[cb * 12]);
        const float4 qa = A[0], qb = A[1], qc = A[2];
        const float ddx = qc.y, ddy = qc.z, ddz = qc.w;
        // center dots (px coeffs qa.x,qa.w,qb.z | py qa.y,qb.x,qb.w | pz qa.z,qb.y,qc.x)
        const float pcx = fmaf(gcz, qb.z, fmaf(gcy, qa.w, gcx * qa.x));
        const float pcy = fmaf(gcz, qb.w, fmaf(gcy, qb.x, gcx * qa.y));
        const float pcz = fmaf(gcz, qc.x, fmaf(gcy, qb.y, gcx * qa.z));
        // 5 linear forms: F0=z, F1=ax*z-x, F2=ax*z+x, F3=ay*z-y, F4=ay*z+y
        const float F1 = fmaf(ax, pcz, -pcx), F2 = fmaf(ax, pcz, pcx);
        const float F3 = fmaf(ay, pcz, -pcy), F4 = fmaf(ay, pcz, pcy);
        // abs-coefficient radii (coupled: accounts x<->z correlation)
        const float r0 = fmaf(ghz, fabsf(qc.x), fmaf(ghy, fabsf(qb.y), ghx * fabsf(qa.z)));
        const float a1x = fmaf(ax, qa.z, -qa.x), a1y = fmaf(ax, qb.y, -qa.w), a1z = fmaf(ax, qc.x, -qb.z);
        const float a2x = fmaf(ax, qa.z,  qa.x), a2y = fmaf(ax, qb.y,  qa.w), a2z = fmaf(ax, qc.x,  qb.z);
        const float a3x = fmaf(ay, qa.z, -qa.y), a3y = fmaf(ay, qb.y, -qb.x), a3z = fmaf(ay, qc.x, -qb.w);
        const float a4x = fmaf(ay, qa.z,  qa.y), a4y = fmaf(ay, qb.y,  qb.x), a4z = fmaf(ay, qc.x,  qb.w);
        const float r1 = fmaf(ghz, fabsf(a1z), fmaf(ghy, fabsf(a1y), ghx * fabsf(a1x)));
        const float r2 = fmaf(ghz, fabsf(a2z), fmaf(ghy, fabsf(a2y), ghx * fabsf(a2x)));
        const float r3 = fmaf(ghz, fabsf(a3z), fmaf(ghy, fabsf(a3y), ghx * fabsf(a3x)));
        const float r4 = fmaf(ghz, fabsf(a4z), fmaf(ghy, fabsf(a4y), ghx * fabsf(a4x)));
        // form offsets
        const float e1 = fmaf(ax, ddz, -ddx), e2 = fmaf(ax, ddz, ddx);
        const float e3 = fmaf(ay, ddz, -ddy), e4 = fmaf(ay, ddz, ddy);

        auto classify = [&](float s, float T, bool& poss, bool& allin) {
            const float v0 = fmaf(s, pcz, -ddz);
            const float v1 = fmaf(s, F1, T - e1);
            const float v2 = fmaf(s, F2, T - e2);
            const float v3 = fmaf(s, F3, T - e3);
            const float v4 = fmaf(s, F4, T - e4);
            const float m0h = fmaf(s, r0, v0), m0l = fmaf(-s, r0, v0);
            const float m1h = fmaf(s, r1, v1), m1l = fmaf(-s, r1, v1);
            const float m2h = fmaf(s, r2, v2), m2l = fmaf(-s, r2, v2);
            const float m3h = fmaf(s, r3, v3), m3l = fmaf(-s, r3, v3);
            const float m4h = fmaf(s, r4, v4), m4l = fmaf(-s, r4, v4);
            // fail-all: box entirely outside one frustum plane
            poss  = !((m0h <= -PAD) | (m1h <= -PAD) | (m2h <= -PAD)
                                    | (m3h <= -PAD) | (m4h <= -PAD));
            // all-in: box strictly inside every plane
            allin = (m0l >= PAD) & (m1l >= PAD) & (m2l >= PAD)
                                 & (m3l >= PAD) & (m4l >= PAD);
        };
        classify(1.0f, T0, po0, in0);
        classify(2.0f, T1, po1, in1);
        classify(4.0f, T2, po2, in2);
    }

    const uint32_t allin0 = (uint32_t)__ballot(in0);
    const uint32_t allin1 = (uint32_t)__ballot(in1);
    const uint32_t allin2 = (uint32_t)__ballot(in2);
    const uint32_t poss0  = (uint32_t)__ballot(po0);
    const uint32_t poss1  = (uint32_t)__ballot(po1);
    const uint32_t poss2  = (uint32_t)__ballot(po2);

    const bool sat0 = (allin0 != 0u), sat1 = (allin1 != 0u), sat2 = (allin2 != 0u);
    bool vA0 = sat0, vA1 = sat1, vA2 = sat2;
    bool vB0 = sat0, vB1 = sat1, vB2 = sat2;

    // ---- phase 2: exact per-cell tests for silhouette cameras only ----
    const uint32_t u0 = sat0 ? 0u : poss0;
    const uint32_t u1 = sat1 ? 0u : poss1;
    const uint32_t u2 = sat2 ? 0u : poss2;
    uint32_t u = u0 | u1 | u2;
    while (u) {
        const int b = __ffs(u) - 1;
        const uint32_t bit = 1u << b;
        u &= u - 1;
        const float4* B = reinterpret_cast<const float4*>(&sRd[b * 12]);
        const float4 qa = B[0], qb = B[1], qc = B[2];
        // shared dots, ascending fma chains (bit-exact path), cells A and B
        const float pxA = fmaf(c0z, qb.z, fmaf(c0y, qa.w, cAx * qa.x));
        const float pyA = fmaf(c0z, qb.w, fmaf(c0y, qb.x, cAx * qa.y));
        const float pzA = fmaf(c0z, qc.x, fmaf(c0y, qb.y, cAx * qa.z));
        const float pxB = fmaf(c0z, qb.z, fmaf(c0y, qa.w, cBx * qa.x));
        const float pyB = fmaf(c0z, qb.w, fmaf(c0y, qb.x, cBx * qa.y));
        const float pzB = fmaf(c0z, qc.x, fmaf(c0y, qb.y, cBx * qa.z));
        if (u0 & bit) {   // cascade 0: cam = p - d
            { const float zz = __fsub_rn(pzA, qc.w);
              const float xx = __fsub_rn(pxA, qc.y);
              const float yy = __fsub_rn(pyA, qc.z);
              vA0 = vA0 | ((zz > 0.0f) & (fabsf(xx) < __fadd_rn(__fmul_rn(ax, zz), T0))
                                       & (fabsf(yy) < __fadd_rn(__fmul_rn(ay, zz), T0))); }
            { const float zz = __fsub_rn(pzB, qc.w);
              const float xx = __fsub_rn(pxB, qc.y);
              const float yy = __fsub_rn(pyB, qc.z);
              vB0 = vB0 | ((zz > 0.0f) & (fabsf(xx) < __fadd_rn(__fmul_rn(ax, zz), T0))
                                       & (fabsf(yy) < __fadd_rn(__fmul_rn(ay, zz), T0))); }
        }
        if (u1 & bit) {   // cascade 1: cam = 2*p - d (exact pow2 scaling)
            { const float zz = fmaf(2.0f, pzA, -qc.w);
              const float xx = fmaf(2.0f, pxA, -qc.y);
              const float yy = fmaf(2.0f, pyA, -qc.z);
              vA1 = vA1 | ((zz > 0.0f) & (fabsf(xx) < __fadd_rn(__fmul_rn(ax, zz), T1))
                                       & (fabsf(yy) < __fadd_rn(__fmul_rn(ay, zz), T1))); }
            { const float zz = fmaf(2.0f, pzB, -qc.w);
              const float xx = fmaf(2.0f, pxB, -qc.y);
              const float yy = fmaf(2.0f, pyB, -qc.z);
              vB1 = vB1 | ((zz > 0.0f) & (fabsf(xx) < __fadd_rn(__fmul_rn(ax, zz), T1))
                                       & (fabsf(yy) < __fadd_rn(__fmul_rn(ay, zz), T1))); }
        }
        if (u2 & bit) {   // cascade 2: cam = 4*p - d
            { const float zz = fmaf(4.0f, pzA, -qc.w);
              const float xx = fmaf(4.0f, pxA, -qc.y);
              const float yy = fmaf(4.0f, pyA, -qc.z);
              vA2 = vA2 | ((zz > 0.0f) & (fabsf(xx) < __fadd_rn(__fmul_rn(ax, zz), T2))
                                       & (fabsf(yy) < __fadd_rn(__fmul_rn(ay, zz), T2))); }
            { const float zz = fmaf(4.0f, pzB, -qc.w);
              const float xx = fmaf(4.0f, pxB, -qc.y);
              const float yy = fmaf(4.0f, pyB, -qc.z);
              vB2 = vB2 | ((zz > 0.0f) & (fabsf(xx) < __fadd_rn(__fmul_rn(ax, zz), T2))
                                       & (fabsf(yy) < __fadd_rn(__fmul_rn(ay, zz), T2))); }
        }
        if (__all(vA0 & vA1 & vA2 & vB0 & vB1 & vB2)) break;
    }

    const int mA = (int)(wbase + (uint32_t)lane);
    const int mB = mA + 64;
    out[mA]              = vA0 ? dg[mA]              : -1.0f;
    out[NCELLS + mA]     = vA1 ? dg[NCELLS + mA]     : -1.0f;
    out[2 * NCELLS + mA] = vA2 ? dg[2 * NCELLS + mA] : -1.0f;
    out[mB]              = vB0 ? dg[mB]              : -1.0f;
    out[NCELLS + mB]     = vB1 ? dg[NCELLS + mB]     : -1.0f;
    out[2 * NCELLS + mB] = vB2 ? dg[2 * NCELLS + mB] : -1.0f;
}

extern "C" void kernel_launch(void* const* d_in, const int* in_sizes, int n_in,
                              void* d_out, int out_size, void* d_ws, size_t ws_size,
                              hipStream_t stream) {
    const float* dg    = (const float*)d_in[0];   // (3, 128^3) f32
    const float* poses = (const float*)d_in[1];   // (32, 4, 4) f32
    const float* intr  = (const float*)d_in[2];   // (4,) f32
    float* out = (float*)d_out;                   // (3, 128^3) f32

    nerf_mark_kernel<<<NCELLS / CPB, BLOCK, 0, stream>>>(dg, poses, intr, out);
}

// Round 11
// 17.810 us; speedup vs baseline: 4.6419x; 1.1652x over previous
//
#include <hip/hip_runtime.h>
#include <stdint.h>

// NeRF "mark untrained cells": out[cas][m] = visible(cas, morton_decode(m)) ? density[cas][m] : -1
//
// Exact per-cell math (HW-validated bit-exact, rounds 3-10) + conservative per-wave SAT
// camera culling (round 10, validated 20.75us / absmax 0.0). This round:
//  * 4 cells/thread as 4 CONSECUTIVE mortons (4*lane+s): wave = 256 contiguous cells
//    (8x8x4 box). Waves 16384 -> 8192: per-wave fixed cost halves again.
//  * float4 epilogue: per cascade one dwordx4 load + one dwordx4 store per lane
//    (16B aligned, 1KB/wave-inst) -- 4x fewer memory instructions.
//  * 256-thread blocks (grid 2048, 8/CU) for load-balance granularity.
// Morton bits of 4*lane+s: x = {s&1, lane b1, lane b4}, y = {s>>1, lane b2, lane b5},
// z = {lane b0, lane b3}.

constexpr int GRIDN  = 128;
constexpr int NCELLS = GRIDN * GRIDN * GRIDN;   // 2097152
constexpr int NCAMS  = 32;
constexpr int BLOCK  = 256;
constexpr int CPB    = BLOCK * 4;               // 1024 cells per block

__device__ __forceinline__ uint32_t compact1by2(uint32_t x) {
    // inverse of reference _part1by2 (valid for 21-bit morton codes)
    x &= 0x09249249u;
    x = (x ^ (x >> 2))  & 0x030c30c3u;
    x = (x ^ (x >> 4))  & 0x0300f00fu;
    x = (x ^ (x >> 8))  & 0x030000ffu;
    x = (x ^ (x >> 16)) & 0x000003ffu;
    return x;
}

__launch_bounds__(BLOCK)
__global__ void nerf_mark_kernel(const float* __restrict__ dg,
                                 const float* __restrict__ poses,
                                 const float* __restrict__ intr,
                                 float* __restrict__ out) {
    // one 48B record per camera: R0..R8, dx, dy, dz  (16B aligned -> 3x ds_read_b128)
    __shared__ __align__(16) float sRd[NCAMS * 12];
    __shared__ float sc0[GRIDN];      // c0 table: round((2i/127 - 1) * S0)
    __shared__ float sax[2];          // cx/fx, cy/fy

    constexpr float S0  = 1.0f - 1.0f / 128.0f;   // 127/128, exact
    constexpr float T0  = 2.0f / 128.0f, T1 = 4.0f / 128.0f, T2 = 8.0f / 128.0f;
    constexpr float PAD = 1e-3f;                  // >> worst-case fp error (~4e-5)

    const int tid = threadIdx.x;
    for (int i = tid; i < NCAMS * 12; i += BLOCK) {   // 384 elems, 256 threads: strided
        int b = i / 12, k = i - b * 12;
        const float* P = poses + b * 16;
        if (k < 9) {
            sRd[i] = P[(k / 3) * 4 + (k % 3)];   // R[j][k']
        } else {
            int kk = k - 9;                       // (t.R)[kk], fma-chain rounding
            sRd[i] = fmaf(P[11], P[8 + kk], fmaf(P[7], P[4 + kk], P[3] * P[kk]));
        }
    }
    if (tid < GRIDN) {
        float w = (2.0f * (float)tid) / 127.0f - 1.0f;   // IEEE ufunc order
        sc0[tid] = __fmul_rn(w, S0);
    }
    if (tid == 0) { sax[0] = intr[2] / intr[0]; sax[1] = intr[3] / intr[1]; }
    __syncthreads();

    const int lane = tid & 63;
    const uint32_t wbase = (uint32_t)blockIdx.x * CPB + ((uint32_t)(tid >> 6)) * 256u;

    // in-wave morton decode: cell = wbase + 4*lane + s
    const int xi = (((lane >> 1) & 1) << 1) | (((lane >> 4) & 1) << 2);  // x offset (bit0 = s&1)
    const int yi = (((lane >> 2) & 1) << 1) | (((lane >> 5) & 1) << 2);  // y offset (bit0 = s>>1)
    const int zi = (lane & 1) | (((lane >> 3) & 1) << 1);
    const int X0 = compact1by2(wbase);            // multiple of 8; wave x: X0..X0+7
    const int Y0 = compact1by2(wbase >> 1);       // multiple of 8
    const int Z0 = compact1by2(wbase >> 2);       // multiple of 4
    const float cx0 = sc0[X0 + xi], cx1 = sc0[X0 + xi + 1];
    const float cy0 = sc0[Y0 + yi], cy1 = sc0[Y0 + yi + 1];
    const float cz  = sc0[Z0 + zi];
    const float ax = sax[0], ay = sax[1];

    // ---- phase 1: wave box (8x8x4 cells) center/halfwidth; sc0 monotonic ----
    const float gxl = sc0[X0], gxh = sc0[X0 + 7];
    const float gyl = sc0[Y0], gyh = sc0[Y0 + 7];
    const float gzl = sc0[Z0], gzh = sc0[Z0 + 3];
    const float gcx = 0.5f * (gxl + gxh), ghx = 0.5f * (gxh - gxl);
    const float gcy = 0.5f * (gyl + gyh), ghy = 0.5f * (gyh - gyl);
    const float gcz = 0.5f * (gzl + gzh), ghz = 0.5f * (gzh - gzl);

    // lane l classifies camera (l & 31) via 5-plane SAT (round-10-validated)
    const int cb = lane & 31;
    bool po0, in0, po1, in1, po2, in2;
    {
        const float4* A = reinterpret_cast<const float4*>(&sRd[cb * 12]);
        const float4 qa = A[0], qb = A[1], qc = A[2];
        const float ddx = qc.y, ddy = qc.z, ddz = qc.w;
        const float pcx = fmaf(gcz, qb.z, fmaf(gcy, qa.w, gcx * qa.x));
        const float pcy = fmaf(gcz, qb.w, fmaf(gcy, qb.x, gcx * qa.y));
        const float pcz = fmaf(gcz, qc.x, fmaf(gcy, qb.y, gcx * qa.z));
        // 5 linear forms: F0=z, F1=ax*z-x, F2=ax*z+x, F3=ay*z-y, F4=ay*z+y
        const float F1 = fmaf(ax, pcz, -pcx), F2 = fmaf(ax, pcz, pcx);
        const float F3 = fmaf(ay, pcz, -pcy), F4 = fmaf(ay, pcz, pcy);
        const float r0 = fmaf(ghz, fabsf(qc.x), fmaf(ghy, fabsf(qb.y), ghx * fabsf(qa.z)));
        const float a1x = fmaf(ax, qa.z, -qa.x), a1y = fmaf(ax, qb.y, -qa.w), a1z = fmaf(ax, qc.x, -qb.z);
        const float a2x = fmaf(ax, qa.z,  qa.x), a2y = fmaf(ax, qb.y,  qa.w), a2z = fmaf(ax, qc.x,  qb.z);
        const float a3x = fmaf(ay, qa.z, -qa.y), a3y = fmaf(ay, qb.y, -qb.x), a3z = fmaf(ay, qc.x, -qb.w);
        const float a4x = fmaf(ay, qa.z,  qa.y), a4y = fmaf(ay, qb.y,  qb.x), a4z = fmaf(ay, qc.x,  qb.w);
        const float r1 = fmaf(ghz, fabsf(a1z), fmaf(ghy, fabsf(a1y), ghx * fabsf(a1x)));
        const float r2 = fmaf(ghz, fabsf(a2z), fmaf(ghy, fabsf(a2y), ghx * fabsf(a2x)));
        const float r3 = fmaf(ghz, fabsf(a3z), fmaf(ghy, fabsf(a3y), ghx * fabsf(a3x)));
        const float r4 = fmaf(ghz, fabsf(a4z), fmaf(ghy, fabsf(a4y), ghx * fabsf(a4x)));
        const float e1 = fmaf(ax, ddz, -ddx), e2 = fmaf(ax, ddz, ddx);
        const float e3 = fmaf(ay, ddz, -ddy), e4 = fmaf(ay, ddz, ddy);

        auto classify = [&](float s, float T, bool& poss, bool& allin) {
            const float v0 = fmaf(s, pcz, -ddz);
            const float v1 = fmaf(s, F1, T - e1);
            const float v2 = fmaf(s, F2, T - e2);
            const float v3 = fmaf(s, F3, T - e3);
            const float v4 = fmaf(s, F4, T - e4);
            const float m0h = fmaf(s, r0, v0), m0l = fmaf(-s, r0, v0);
            const float m1h = fmaf(s, r1, v1), m1l = fmaf(-s, r1, v1);
            const float m2h = fmaf(s, r2, v2), m2l = fmaf(-s, r2, v2);
            const float m3h = fmaf(s, r3, v3), m3l = fmaf(-s, r3, v3);
            const float m4h = fmaf(s, r4, v4), m4l = fmaf(-s, r4, v4);
            poss  = !((m0h <= -PAD) | (m1h <= -PAD) | (m2h <= -PAD)
                                    | (m3h <= -PAD) | (m4h <= -PAD));
            allin = (m0l >= PAD) & (m1l >= PAD) & (m2l >= PAD)
                                 & (m3l >= PAD) & (m4l >= PAD);
        };
        classify(1.0f, T0, po0, in0);
        classify(2.0f, T1, po1, in1);
        classify(4.0f, T2, po2, in2);
    }

    const uint32_t allin0 = (uint32_t)__ballot(in0);
    const uint32_t allin1 = (uint32_t)__ballot(in1);
    const uint32_t allin2 = (uint32_t)__ballot(in2);
    const uint32_t poss0  = (uint32_t)__ballot(po0);
    const uint32_t poss1  = (uint32_t)__ballot(po1);
    const uint32_t poss2  = (uint32_t)__ballot(po2);

    const bool sat0 = (allin0 != 0u), sat1 = (allin1 != 0u), sat2 = (allin2 != 0u);
    // per-cell visibility, cells s=0..3: (x0,y0),(x1,y0),(x0,y1),(x1,y1)
    bool va0 = sat0, vb0 = sat0, vc0 = sat0, vd0 = sat0;
    bool va1 = sat1, vb1 = sat1, vc1 = sat1, vd1 = sat1;
    bool va2 = sat2, vb2 = sat2, vc2 = sat2, vd2 = sat2;

    // ---- phase 2: exact per-cell tests for silhouette cameras only ----
    const uint32_t u0 = sat0 ? 0u : poss0;
    const uint32_t u1 = sat1 ? 0u : poss1;
    const uint32_t u2 = sat2 ? 0u : poss2;
    uint32_t u = u0 | u1 | u2;
    while (u) {
        const int b = __ffs(u) - 1;
        const uint32_t bit = 1u << b;
        u &= u - 1;
        const float4* B = reinterpret_cast<const float4*>(&sRd[b * 12]);
        const float4 qa = B[0], qb = B[1], qc = B[2];
        // 4 cells share chain prefixes; each cell's chain is the bit-exact validated
        // sequence fmaf(cz, R2k, fmaf(cy, R1k, cx*R0k))
        const float i0x = cx0 * qa.x, i1x = cx1 * qa.x;
        const float i0y = cx0 * qa.y, i1y = cx1 * qa.y;
        const float i0z = cx0 * qa.z, i1z = cx1 * qa.z;
        const float pxa = fmaf(cz, qb.z, fmaf(cy0, qa.w, i0x));
        const float pxb = fmaf(cz, qb.z, fmaf(cy0, qa.w, i1x));
        const float pxc = fmaf(cz, qb.z, fmaf(cy1, qa.w, i0x));
        const float pxd = fmaf(cz, qb.z, fmaf(cy1, qa.w, i1x));
        const float pya = fmaf(cz, qb.w, fmaf(cy0, qb.x, i0y));
        const float pyb = fmaf(cz, qb.w, fmaf(cy0, qb.x, i1y));
        const float pyc = fmaf(cz, qb.w, fmaf(cy1, qb.x, i0y));
        const float pyd = fmaf(cz, qb.w, fmaf(cy1, qb.x, i1y));
        const float pza = fmaf(cz, qc.x, fmaf(cy0, qb.y, i0z));
        const float pzb = fmaf(cz, qc.x, fmaf(cy0, qb.y, i1z));
        const float pzc = fmaf(cz, qc.x, fmaf(cy1, qb.y, i0z));
        const float pzd = fmaf(cz, qc.x, fmaf(cy1, qb.y, i1z));

        #define CELL_TEST0(px, py, pz, v) {                                          \
            const float zz = __fsub_rn(pz, qc.w);                                    \
            const float xx = __fsub_rn(px, qc.y);                                    \
            const float yy = __fsub_rn(py, qc.z);                                    \
            v = v | ((zz > 0.0f) & (fabsf(xx) < __fadd_rn(__fmul_rn(ax, zz), T0))    \
                                 & (fabsf(yy) < __fadd_rn(__fmul_rn(ay, zz), T0))); }
        #define CELL_TESTS(S, T, px, py, pz, v) {                                    \
            const float zz = fmaf(S, pz, -qc.w);                                     \
            const float xx = fmaf(S, px, -qc.y);                                     \
            const float yy = fmaf(S, py, -qc.z);                                     \
            v = v | ((zz > 0.0f) & (fabsf(xx) < __fadd_rn(__fmul_rn(ax, zz), T))     \
                                 & (fabsf(yy) < __fadd_rn(__fmul_rn(ay, zz), T))); }

        if (u0 & bit) {
            CELL_TEST0(pxa, pya, pza, va0); CELL_TEST0(pxb, pyb, pzb, vb0);
            CELL_TEST0(pxc, pyc, pzc, vc0); CELL_TEST0(pxd, pyd, pzd, vd0);
        }
        if (u1 & bit) {
            CELL_TESTS(2.0f, T1, pxa, pya, pza, va1); CELL_TESTS(2.0f, T1, pxb, pyb, pzb, vb1);
            CELL_TESTS(2.0f, T1, pxc, pyc, pzc, vc1); CELL_TESTS(2.0f, T1, pxd, pyd, pzd, vd1);
        }
        if (u2 & bit) {
            CELL_TESTS(4.0f, T2, pxa, pya, pza, va2); CELL_TESTS(4.0f, T2, pxb, pyb, pzb, vb2);
            CELL_TESTS(4.0f, T2, pxc, pyc, pzc, vc2); CELL_TESTS(4.0f, T2, pxd, pyd, pzd, vd2);
        }
        if (__all(va0 & vb0 & vc0 & vd0 & va1 & vb1 & vc1 & vd1 & va2 & vb2 & vc2 & vd2))
            break;
        #undef CELL_TEST0
        #undef CELL_TESTS
    }

    // ---- epilogue: float4 per cascade (cells 4*lane .. 4*lane+3 consecutive) ----
    const int mA = (int)(wbase + 4u * (uint32_t)lane);
    {
        const float4 d = *reinterpret_cast<const float4*>(dg + mA);
        float4 o;
        o.x = va0 ? d.x : -1.0f; o.y = vb0 ? d.y : -1.0f;
        o.z = vc0 ? d.z : -1.0f; o.w = vd0 ? d.w : -1.0f;
        *reinterpret_cast<float4*>(out + mA) = o;
    }
    {
        const float4 d = *reinterpret_cast<const float4*>(dg + NCELLS + mA);
        float4 o;
        o.x = va1 ? d.x : -1.0f; o.y = vb1 ? d.y : -1.0f;
        o.z = vc1 ? d.z : -1.0f; o.w = vd1 ? d.w : -1.0f;
        *reinterpret_cast<float4*>(out + NCELLS + mA) = o;
    }
    {
        const float4 d = *reinterpret_cast<const float4*>(dg + 2 * NCELLS + mA);
        float4 o;
        o.x = va2 ? d.x : -1.0f; o.y = vb2 ? d.y : -1.0f;
        o.z = vc2 ? d.z : -1.0f; o.w = vd2 ? d.w : -1.0f;
        *reinterpret_cast<float4*>(out + 2 * NCELLS + mA) = o;
    }
}

extern "C" void kernel_launch(void* const* d_in, const int* in_sizes, int n_in,
                              void* d_out, int out_size, void* d_ws, size_t ws_size,
                              hipStream_t stream) {
    const float* dg    = (const float*)d_in[0];   // (3, 128^3) f32
    const float* poses = (const float*)d_in[1];   // (32, 4, 4) f32
    const float* intr  = (const float*)d_in[2];   // (4,) f32
    float* out = (float*)d_out;                   // (3, 128^3) f32

    nerf_mark_kernel<<<NCELLS / CPB, BLOCK, 0, stream>>>(dg, poses, intr, out);
}

// Round 12
// 15.740 us; speedup vs baseline: 5.2524x; 1.1315x over previous
//
#include <hip/hip_runtime.h>
#include <stdint.h>

// NeRF "mark untrained cells": out[cas][m] = visible(cas, morton_decode(m)) ? density[cas][m] : -1
//
// Exact per-cell math (HW-validated bit-exact, rounds 3-11) + conservative per-wave SAT
// camera culling (rounds 10/11, validated / absmax 0.0). Lever history: waves 32768->16384
// ->8192 gave 24.0 -> 20.75 -> 17.8 us. This round: 8 cells/thread (2x2x2 cube per lane),
// wave = 512 contiguous Morton cells (8x8x8 box), waves -> 4096.
//  * dot-chain sharing improves: 2 muls + 4 mid-fma + 8 final-fma per component
//    for 8 cells (5.25 ops/cell vs 7.5 in round 11); per-cell chain bit-identical.
//  * epilogue: 2x float4 per cascade (8 consecutive cells per lane).
// Morton bits of 8*lane+s: x = {s&1, lane b0, lane b3}, y = {s>>1&1, lane b1, lane b4},
// z = {s>>2, lane b2, lane b5}.

constexpr int GRIDN  = 128;
constexpr int NCELLS = GRIDN * GRIDN * GRIDN;   // 2097152
constexpr int NCAMS  = 32;
constexpr int BLOCK  = 256;
constexpr int CPB    = BLOCK * 8;               // 2048 cells per block

__device__ __forceinline__ uint32_t compact1by2(uint32_t x) {
    // inverse of reference _part1by2 (valid for 21-bit morton codes)
    x &= 0x09249249u;
    x = (x ^ (x >> 2))  & 0x030c30c3u;
    x = (x ^ (x >> 4))  & 0x0300f00fu;
    x = (x ^ (x >> 8))  & 0x030000ffu;
    x = (x ^ (x >> 16)) & 0x000003ffu;
    return x;
}

__launch_bounds__(BLOCK)
__global__ void nerf_mark_kernel(const float* __restrict__ dg,
                                 const float* __restrict__ poses,
                                 const float* __restrict__ intr,
                                 float* __restrict__ out) {
    // one 48B record per camera: R0..R8, dx, dy, dz  (16B aligned -> 3x ds_read_b128)
    __shared__ __align__(16) float sRd[NCAMS * 12];
    __shared__ float sc0[GRIDN];      // c0 table: round((2i/127 - 1) * S0)
    __shared__ float sax[2];          // cx/fx, cy/fy

    constexpr float S0  = 1.0f - 1.0f / 128.0f;   // 127/128, exact
    constexpr float T0  = 2.0f / 128.0f, T1 = 4.0f / 128.0f, T2 = 8.0f / 128.0f;
    constexpr float PAD = 1e-3f;                  // >> worst-case fp error (~4e-5)

    const int tid = threadIdx.x;
    for (int i = tid; i < NCAMS * 12; i += BLOCK) {   // 384 elems, 256 threads: strided
        int b = i / 12, k = i - b * 12;
        const float* P = poses + b * 16;
        if (k < 9) {
            sRd[i] = P[(k / 3) * 4 + (k % 3)];   // R[j][k']
        } else {
            int kk = k - 9;                       // (t.R)[kk], fma-chain rounding
            sRd[i] = fmaf(P[11], P[8 + kk], fmaf(P[7], P[4 + kk], P[3] * P[kk]));
        }
    }
    if (tid < GRIDN) {
        float w = (2.0f * (float)tid) / 127.0f - 1.0f;   // IEEE ufunc order
        sc0[tid] = __fmul_rn(w, S0);
    }
    if (tid == 0) { sax[0] = intr[2] / intr[0]; sax[1] = intr[3] / intr[1]; }
    __syncthreads();

    const int lane = tid & 63;
    const uint32_t wbase = (uint32_t)blockIdx.x * CPB + ((uint32_t)(tid >> 6)) * 512u;

    // in-wave morton decode: cell = wbase + 8*lane + s, s in [0,8)
    const int xi = ((lane & 1) << 1) | (((lane >> 3) & 1) << 2);
    const int yi = (((lane >> 1) & 1) << 1) | (((lane >> 4) & 1) << 2);
    const int zi = (((lane >> 2) & 1) << 1) | (((lane >> 5) & 1) << 2);
    const int X0 = compact1by2(wbase);            // multiple of 8; wave box x: X0..X0+7
    const int Y0 = compact1by2(wbase >> 1);       // multiple of 8
    const int Z0 = compact1by2(wbase >> 2);       // multiple of 8
    const float cxv[2] = { sc0[X0 + xi], sc0[X0 + xi + 1] };
    const float cyv[2] = { sc0[Y0 + yi], sc0[Y0 + yi + 1] };
    const float czv[2] = { sc0[Z0 + zi], sc0[Z0 + zi + 1] };
    const float ax = sax[0], ay = sax[1];

    // ---- phase 1: wave box (8x8x8 cells) center/halfwidth; sc0 monotonic ----
    const float gxl = sc0[X0], gxh = sc0[X0 + 7];
    const float gyl = sc0[Y0], gyh = sc0[Y0 + 7];
    const float gzl = sc0[Z0], gzh = sc0[Z0 + 7];
    const float gcx = 0.5f * (gxl + gxh), ghx = 0.5f * (gxh - gxl);
    const float gcy = 0.5f * (gyl + gyh), ghy = 0.5f * (gyh - gyl);
    const float gcz = 0.5f * (gzl + gzh), ghz = 0.5f * (gzh - gzl);

    // lane l classifies camera (l & 31) via 5-plane SAT (rounds 10/11 validated)
    const int cb = lane & 31;
    bool po0, in0, po1, in1, po2, in2;
    {
        const float4* A = reinterpret_cast<const float4*>(&sRd[cb * 12]);
        const float4 qa = A[0], qb = A[1], qc = A[2];
        const float ddx = qc.y, ddy = qc.z, ddz = qc.w;
        const float pcx = fmaf(gcz, qb.z, fmaf(gcy, qa.w, gcx * qa.x));
        const float pcy = fmaf(gcz, qb.w, fmaf(gcy, qb.x, gcx * qa.y));
        const float pcz = fmaf(gcz, qc.x, fmaf(gcy, qb.y, gcx * qa.z));
        // 5 linear forms: F0=z, F1=ax*z-x, F2=ax*z+x, F3=ay*z-y, F4=ay*z+y
        const float F1 = fmaf(ax, pcz, -pcx), F2 = fmaf(ax, pcz, pcx);
        const float F3 = fmaf(ay, pcz, -pcy), F4 = fmaf(ay, pcz, pcy);
        const float r0 = fmaf(ghz, fabsf(qc.x), fmaf(ghy, fabsf(qb.y), ghx * fabsf(qa.z)));
        const float a1x = fmaf(ax, qa.z, -qa.x), a1y = fmaf(ax, qb.y, -qa.w), a1z = fmaf(ax, qc.x, -qb.z);
        const float a2x = fmaf(ax, qa.z,  qa.x), a2y = fmaf(ax, qb.y,  qa.w), a2z = fmaf(ax, qc.x,  qb.z);
        const float a3x = fmaf(ay, qa.z, -qa.y), a3y = fmaf(ay, qb.y, -qb.x), a3z = fmaf(ay, qc.x, -qb.w);
        const float a4x = fmaf(ay, qa.z,  qa.y), a4y = fmaf(ay, qb.y,  qb.x), a4z = fmaf(ay, qc.x,  qb.w);
        const float r1 = fmaf(ghz, fabsf(a1z), fmaf(ghy, fabsf(a1y), ghx * fabsf(a1x)));
        const float r2 = fmaf(ghz, fabsf(a2z), fmaf(ghy, fabsf(a2y), ghx * fabsf(a2x)));
        const float r3 = fmaf(ghz, fabsf(a3z), fmaf(ghy, fabsf(a3y), ghx * fabsf(a3x)));
        const float r4 = fmaf(ghz, fabsf(a4z), fmaf(ghy, fabsf(a4y), ghx * fabsf(a4x)));
        const float e1 = fmaf(ax, ddz, -ddx), e2 = fmaf(ax, ddz, ddx);
        const float e3 = fmaf(ay, ddz, -ddy), e4 = fmaf(ay, ddz, ddy);

        auto classify = [&](float s, float T, bool& poss, bool& allin) {
            const float v0 = fmaf(s, pcz, -ddz);
            const float v1 = fmaf(s, F1, T - e1);
            const float v2 = fmaf(s, F2, T - e2);
            const float v3 = fmaf(s, F3, T - e3);
            const float v4 = fmaf(s, F4, T - e4);
            const float m0h = fmaf(s, r0, v0), m0l = fmaf(-s, r0, v0);
            const float m1h = fmaf(s, r1, v1), m1l = fmaf(-s, r1, v1);
            const float m2h = fmaf(s, r2, v2), m2l = fmaf(-s, r2, v2);
            const float m3h = fmaf(s, r3, v3), m3l = fmaf(-s, r3, v3);
            const float m4h = fmaf(s, r4, v4), m4l = fmaf(-s, r4, v4);
            poss  = !((m0h <= -PAD) | (m1h <= -PAD) | (m2h <= -PAD)
                                    | (m3h <= -PAD) | (m4h <= -PAD));
            allin = (m0l >= PAD) & (m1l >= PAD) & (m2l >= PAD)
                                 & (m3l >= PAD) & (m4l >= PAD);
        };
        classify(1.0f, T0, po0, in0);
        classify(2.0f, T1, po1, in1);
        classify(4.0f, T2, po2, in2);
    }

    const uint32_t allin0 = (uint32_t)__ballot(in0);
    const uint32_t allin1 = (uint32_t)__ballot(in1);
    const uint32_t allin2 = (uint32_t)__ballot(in2);
    const uint32_t poss0  = (uint32_t)__ballot(po0);
    const uint32_t poss1  = (uint32_t)__ballot(po1);
    const uint32_t poss2  = (uint32_t)__ballot(po2);

    const bool sat0 = (allin0 != 0u), sat1 = (allin1 != 0u), sat2 = (allin2 != 0u);
    // per-cell visibility; cell s = x + 2y + 4z (matches memory order 8*lane+s)
    bool v0[8], v1[8], v2[8];
    #pragma unroll
    for (int s = 0; s < 8; ++s) { v0[s] = sat0; v1[s] = sat1; v2[s] = sat2; }

    // ---- phase 2: exact per-cell tests for silhouette cameras only ----
    const uint32_t u0 = sat0 ? 0u : poss0;
    const uint32_t u1 = sat1 ? 0u : poss1;
    const uint32_t u2 = sat2 ? 0u : poss2;
    uint32_t u = u0 | u1 | u2;
    while (u) {
        const int b = __ffs(u) - 1;
        const uint32_t bit = 1u << b;
        u &= u - 1;
        const float4* B = reinterpret_cast<const float4*>(&sRd[b * 12]);
        const float4 qa = B[0], qb = B[1], qc = B[2];

        // 8 cells share chain prefixes; each cell's full chain is the bit-exact
        // validated sequence fmaf(cz, R2k, fmaf(cy, R1k, cx*R0k)).
        float p0[8], p1[8], p2[8];
        #pragma unroll
        for (int x = 0; x < 2; ++x) {
            const float i0 = cxv[x] * qa.x;
            const float i1 = cxv[x] * qa.y;
            const float i2 = cxv[x] * qa.z;
            #pragma unroll
            for (int y = 0; y < 2; ++y) {
                const float j0 = fmaf(cyv[y], qa.w, i0);
                const float j1 = fmaf(cyv[y], qb.x, i1);
                const float j2 = fmaf(cyv[y], qb.y, i2);
                #pragma unroll
                for (int z = 0; z < 2; ++z) {
                    const int s = x + 2 * y + 4 * z;
                    p0[s] = fmaf(czv[z], qb.z, j0);
                    p1[s] = fmaf(czv[z], qb.w, j1);
                    p2[s] = fmaf(czv[z], qc.x, j2);
                }
            }
        }

        if (u0 & bit) {   // cascade 0: cam = p - d
            #pragma unroll
            for (int s = 0; s < 8; ++s) {
                const float zz = __fsub_rn(p2[s], qc.w);
                const float xx = __fsub_rn(p0[s], qc.y);
                const float yy = __fsub_rn(p1[s], qc.z);
                v0[s] = v0[s] | ((zz > 0.0f)
                              & (fabsf(xx) < __fadd_rn(__fmul_rn(ax, zz), T0))
                              & (fabsf(yy) < __fadd_rn(__fmul_rn(ay, zz), T0)));
            }
        }
        if (u1 & bit) {   // cascade 1: cam = 2*p - d (exact pow2 scaling)
            #pragma unroll
            for (int s = 0; s < 8; ++s) {
                const float zz = fmaf(2.0f, p2[s], -qc.w);
                const float xx = fmaf(2.0f, p0[s], -qc.y);
                const float yy = fmaf(2.0f, p1[s], -qc.z);
                v1[s] = v1[s] | ((zz > 0.0f)
                              & (fabsf(xx) < __fadd_rn(__fmul_rn(ax, zz), T1))
                              & (fabsf(yy) < __fadd_rn(__fmul_rn(ay, zz), T1)));
            }
        }
        if (u2 & bit) {   // cascade 2: cam = 4*p - d
            #pragma unroll
            for (int s = 0; s < 8; ++s) {
                const float zz = fmaf(4.0f, p2[s], -qc.w);
                const float xx = fmaf(4.0f, p0[s], -qc.y);
                const float yy = fmaf(4.0f, p1[s], -qc.z);
                v2[s] = v2[s] | ((zz > 0.0f)
                              & (fabsf(xx) < __fadd_rn(__fmul_rn(ax, zz), T2))
                              & (fabsf(yy) < __fadd_rn(__fmul_rn(ay, zz), T2)));
            }
        }

        bool allv = true;
        #pragma unroll
        for (int s = 0; s < 8; ++s) allv = allv & v0[s] & v1[s] & v2[s];
        if (__all(allv)) break;
    }

    // ---- epilogue: 2x float4 per cascade (cells 8*lane .. 8*lane+7 consecutive) ----
    const int mA = (int)(wbase + 8u * (uint32_t)lane);
    #pragma unroll
    for (int cas = 0; cas < 3; ++cas) {
        const bool* v = (cas == 0) ? v0 : (cas == 1) ? v1 : v2;
        const float* src = dg + cas * NCELLS + mA;
        float* dst = out + cas * NCELLS + mA;
        const float4 dlo = *reinterpret_cast<const float4*>(src);
        const float4 dhi = *reinterpret_cast<const float4*>(src + 4);
        float4 olo, ohi;
        olo.x = v[0] ? dlo.x : -1.0f; olo.y = v[1] ? dlo.y : -1.0f;
        olo.z = v[2] ? dlo.z : -1.0f; olo.w = v[3] ? dlo.w : -1.0f;
        ohi.x = v[4] ? dhi.x : -1.0f; ohi.y = v[5] ? dhi.y : -1.0f;
        ohi.z = v[6] ? dhi.z : -1.0f; ohi.w = v[7] ? dhi.w : -1.0f;
        *reinterpret_cast<float4*>(dst)     = olo;
        *reinterpret_cast<float4*>(dst + 4) = ohi;
    }
}

extern "C" void kernel_launch(void* const* d_in, const int* in_sizes, int n_in,
                              void* d_out, int out_size, void* d_ws, size_t ws_size,
                              hipStream_t stream) {
    const float* dg    = (const float*)d_in[0];   // (3, 128^3) f32
    const float* poses = (const float*)d_in[1];   // (32, 4, 4) f32
    const float* intr  = (const float*)d_in[2];   // (4,) f32
    float* out = (float*)d_out;                   // (3, 128^3) f32

    nerf_mark_kernel<<<NCELLS / CPB, BLOCK, 0, stream>>>(dg, poses, intr, out);
}